// Round 7
// baseline (802.843 us; speedup 1.0000x reference)
//
#include <hip/hip_runtime.h>
#include <math.h>

#define E_    3
#define QE_   60000
#define QTOT  180000      // E_*QE_
#define P_    40
#define H_    20
#define NIMG_ 1800
#define NNZ_  14400000
#define BLK   256
#define NB    704         // ceil(QTOT/BLK)

// column-window partition for the sparse force accumulation
#define CW_BITS 12
#define CW      4096                  // cols per window (16 KB LDS accumulator)
#define NBIN    132                   // ceil(3*QTOT / CW)
#define SUBS    8                     // sub-slices per bin in force kernel
#define SC      8192                  // nnz items per chunk
#define NSB     1758                  // ceil(NNZ_/SC)  (input chunking)

// row-slice partition: 131072 dE rows = 512 KB per slice -> fits XCD L2
#define SLICE_SHIFT 17
#define NSLICE  55                    // ceil(7.2M / 131072)

// v9: 4-way producer split of slice cursors (cuts same-address atomic chain
// 1758 -> ~440) + exact-prepass bin offsets (cuts fscatter4's chain to ZERO)
#define GSPLIT  4
#define NREG    220                   // GSPLIT * NSLICE
#define CAPS4   68096                 // per-region item capacity (65536 + 10 sigma)
#define NCH4    2048                  // chunk-table width (actual ~1980)
#define NGMAX   384                   // per-XCD-group chunk list capacity
#define FS_GRID 1792                  // 8 XCD groups x 224 blocks
#define FS_PERX 224

// ctrl int offsets
#define C_SCUR  0      // [220]   region cursors (= counts after slice_scatter)
#define C_GCNT  256    // [8]     per-XCD-group chunk counts
#define C_NCH   264    // [1]     total chunks
#define C_CHID  512    // [2048]  chunk -> packed (region<<8)|c
#define C_GRP   2560   // [8*384] per-XCD-group chunk id lists
#define C_INTS  5632

typedef int   vi4 __attribute__((ext_vector_type(4)));
typedef float vf4 __attribute__((ext_vector_type(4)));
typedef unsigned uint32;

// ---------------- zero init -------------------------------------------------
__global__ void zero_kernel(float* __restrict__ out, int n) {
    int i = blockIdx.x * blockDim.x + threadIdx.x;
    if (i < n) out[i] = 0.0f;
}
__global__ void zero_ctrl_kernel(int* __restrict__ ctrl) {
    ctrl[threadIdx.x] = 0;   // launched with 512 threads: C_SCUR+C_GCNT+C_NCH
}

// ---------------- stable counting sort for atom ranks ----------------------
__global__ void hist_kernel(const int* __restrict__ img, int* __restrict__ g_hist) {
    __shared__ int h[NIMG_];
    const int t = threadIdx.x, b = blockIdx.x;
    for (int v = t; v < NIMG_; v += BLK) h[v] = 0;
    __syncthreads();
    int a = b * BLK + t;
    if (a < QTOT) atomicAdd(&h[img[a]], 1);
    __syncthreads();
    for (int v = t; v < NIMG_; v += BLK) g_hist[v * NB + b] = h[v];
}

__global__ void scan_blocks_kernel(int* __restrict__ g_hist, int* __restrict__ g_total) {
    __shared__ int s[BLK];
    const int v = blockIdx.x, t = threadIdx.x;
    int carry = 0;
    for (int c = 0; c < NB; c += BLK) {
        int idx = c + t;
        int val = (idx < NB) ? g_hist[v * NB + idx] : 0;
        s[t] = val; __syncthreads();
        for (int off = 1; off < BLK; off <<= 1) {
            int tmp = (t >= off) ? s[t - off] : 0;
            __syncthreads();
            s[t] += tmp;
            __syncthreads();
        }
        int excl = s[t] - val;
        int tot  = s[BLK - 1];
        if (idx < NB) g_hist[v * NB + idx] = carry + excl;
        carry += tot;
        __syncthreads();
    }
    if (t == 0) g_total[v] = carry;
}

__global__ void scan_buckets_kernel(const int* __restrict__ g_total, int* __restrict__ g_base) {
    __shared__ int s[BLK];
    const int t = threadIdx.x;
    int carry = 0;
    for (int c = 0; c < NIMG_; c += BLK) {
        int idx = c + t;
        int val = (idx < NIMG_) ? g_total[idx] : 0;
        s[t] = val; __syncthreads();
        for (int off = 1; off < BLK; off <<= 1) {
            int tmp = (t >= off) ? s[t - off] : 0;
            __syncthreads();
            s[t] += tmp;
            __syncthreads();
        }
        if (idx < NIMG_) g_base[idx] = carry + (s[t] - val);
        carry += s[BLK - 1];
        __syncthreads();
    }
}

__global__ void rank_kernel(const int* __restrict__ img, const int* __restrict__ g_hist,
                            const int* __restrict__ g_base, int* __restrict__ rank) {
    __shared__ int simg[BLK];
    const int t = threadIdx.x, b = blockIdx.x;
    int a = b * BLK + t;
    int v = (a < QTOT) ? img[a] : -1;
    simg[t] = v;
    __syncthreads();
    if (a < QTOT) {
        int local = 0;
        for (int j = 0; j < t; ++j) {
            if (simg[j] == v) local++;
        }
        rank[a] = g_base[v] + g_hist[v * NB + b] + local;
    }
}

// ---------------- per-atom MLP forward + backward ---------------------------
__global__ __launch_bounds__(BLK) void mlp_kernel(
    const float* __restrict__ fps, const float* __restrict__ W1, const float* __restrict__ b1,
    const float* __restrict__ W2, const float* __restrict__ b2, const float* __restrict__ W3,
    const float* __restrict__ b3, const int* __restrict__ img, const int* __restrict__ rank,
    float* __restrict__ energy, float* __restrict__ dEflat)
{
    __shared__ float sW1[P_ * H_], sW2[H_ * H_], sW3[H_], sB1[H_], sB2[H_];
    __shared__ float sB3;
    const int e = blockIdx.y;
    const int t = threadIdx.x;
    for (int i = t; i < P_ * H_; i += BLK) sW1[i] = W1[e * P_ * H_ + i];
    for (int i = t; i < H_ * H_; i += BLK) sW2[i] = W2[e * H_ * H_ + i];
    if (t < H_) { sW3[t] = W3[e * H_ + t]; sB1[t] = b1[e * H_ + t]; sB2[t] = b2[e * H_ + t]; }
    if (t == 0) sB3 = b3[e];
    __syncthreads();

    int q = blockIdx.x * BLK + t;
    if (q >= QE_) return;
    int a = e * QE_ + q;

    const vf4* xp = (const vf4*)(fps + (size_t)a * P_);
    float x[P_];
    #pragma unroll
    for (int p = 0; p < P_; p += 4) {
        vf4 v4 = __builtin_nontemporal_load(xp + (p >> 2));
        x[p] = v4.x; x[p+1] = v4.y; x[p+2] = v4.z; x[p+3] = v4.w;
    }

    float h1v[H_], h2v[H_];
    #pragma unroll
    for (int i = 0; i < H_; ++i) {
        float z = sB1[i];
        #pragma unroll
        for (int p = 0; p < P_; ++p) z += x[p] * sW1[p * H_ + i];
        h1v[i] = tanhf(z);
    }
    #pragma unroll
    for (int i = 0; i < H_; ++i) {
        float z = sB2[i];
        #pragma unroll
        for (int j = 0; j < H_; ++j) z += h1v[j] * sW2[j * H_ + i];
        h2v[i] = tanhf(z);
    }
    float ea = sB3;
    #pragma unroll
    for (int i = 0; i < H_; ++i) ea += h2v[i] * sW3[i];
    atomicAdd(&energy[img[a]], ea);

    float dz2[H_];
    #pragma unroll
    for (int i = 0; i < H_; ++i) dz2[i] = sW3[i] * (1.0f - h2v[i] * h2v[i]);
    float dz1[H_];
    #pragma unroll
    for (int i = 0; i < H_; ++i) {
        float d = 0.0f;
        #pragma unroll
        for (int j = 0; j < H_; ++j) d += sW2[i * H_ + j] * dz2[j];
        dz1[i] = d * (1.0f - h1v[i] * h1v[i]);
    }
    float* op = dEflat + (size_t)rank[a] * P_;
    #pragma unroll
    for (int p = 0; p < P_; p += 4) {
        float4 v4;
        float d0 = 0.f, d1 = 0.f, d2 = 0.f, d3 = 0.f;
        #pragma unroll
        for (int i = 0; i < H_; ++i) {
            d0 += sW1[(p    ) * H_ + i] * dz1[i];
            d1 += sW1[(p + 1) * H_ + i] * dz1[i];
            d2 += sW1[(p + 2) * H_ + i] * dz1[i];
            d3 += sW1[(p + 3) * H_ + i] * dz1[i];
        }
        v4.x = d0; v4.y = d1; v4.z = d2; v4.w = d3;
        *(float4*)(op + p) = v4;   // re-read by fscatter gather (L2-local)
    }
}

// ============ v9 stage A: slice_scatter with 4-way split cursors ============
// item = { (val15<<17)|rowLocal17 , col }; dest region = (blockIdx&3, slice)
__global__ __launch_bounds__(BLK) void slice_scatter_kernel(
    const int* __restrict__ rows, const int* __restrict__ cols, const float* __restrict__ vals,
    int* __restrict__ ctrl, uint2* __restrict__ items)
{
    __shared__ uint32 srow[SC];          // 32 KB staged rows
    __shared__ int h[NSLICE], lcur[NSLICE], gbase[NSLICE];
    const int t = threadIdx.x, b = blockIdx.x;
    const int g = b & (GSPLIT - 1);
    const int base = b * SC;
    const int len = min(SC, NNZ_ - base);
    const bool full = (len == SC);

    if (t < NSLICE) h[t] = 0;
    __syncthreads();
    if (full) {
        const vi4* r4 = (const vi4*)(rows + base);
        #pragma unroll
        for (int j = 0; j < SC / (BLK * 4); ++j) {
            int idx = j * BLK + t;
            vi4 rr = __builtin_nontemporal_load(r4 + idx);
            srow[idx * 4 + 0] = (uint32)rr.x; atomicAdd(&h[rr.x >> SLICE_SHIFT], 1);
            srow[idx * 4 + 1] = (uint32)rr.y; atomicAdd(&h[rr.y >> SLICE_SHIFT], 1);
            srow[idx * 4 + 2] = (uint32)rr.z; atomicAdd(&h[rr.z >> SLICE_SHIFT], 1);
            srow[idx * 4 + 3] = (uint32)rr.w; atomicAdd(&h[rr.w >> SLICE_SHIFT], 1);
        }
    } else {
        for (int j = t; j < len; j += BLK) {
            int r = rows[base + j];
            srow[j] = (uint32)r;
            atomicAdd(&h[r >> SLICE_SHIFT], 1);
        }
    }
    __syncthreads();
    if (t < NSLICE) {
        lcur[t] = 0;
        gbase[t] = (h[t] > 0) ? atomicAdd(&ctrl[C_SCUR + g * NSLICE + t], h[t]) : 0;
    }
    __syncthreads();
    if (full) {
        const vi4* c4 = (const vi4*)(cols + base);
        const vi4* v4 = (const vi4*)(vals + base);
        #pragma unroll 2
        for (int j = 0; j < SC / (BLK * 4); ++j) {
            int idx = j * BLK + t;
            vi4 cc = __builtin_nontemporal_load(c4 + idx);
            vi4 vv = __builtin_nontemporal_load(v4 + idx);
            #define EMIT(K, CI, VB)                                                \
            {                                                                      \
                uint32 r = srow[idx * 4 + K];                                      \
                int sl = (int)(r >> SLICE_SHIFT);                                  \
                int pos = gbase[sl] + atomicAdd(&lcur[sl], 1);                     \
                uint32 v15 = (((uint32)(VB)) + 0x10000u) >> 17;                    \
                items[(size_t)(g * NSLICE + sl) * CAPS4 + pos] =                   \
                    make_uint2((v15 << 17) | (r & 0x1FFFFu), (uint32)(CI));        \
            }
            EMIT(0, cc.x, vv.x)
            EMIT(1, cc.y, vv.y)
            EMIT(2, cc.z, vv.z)
            EMIT(3, cc.w, vv.w)
        }
    } else {
        for (int j = t; j < len; j += BLK) {
            uint32 r = srow[j];
            int sl = (int)(r >> SLICE_SHIFT);
            int pos = gbase[sl] + atomicAdd(&lcur[sl], 1);
            uint32 vb = ((const uint32*)vals)[base + j];
            uint32 v15 = (vb + 0x10000u) >> 17;
            items[(size_t)(g * NSLICE + sl) * CAPS4 + pos] =
                make_uint2((v15 << 17) | (r & 0x1FFFFu), (uint32)cols[base + j]);
        }
    }
}

// plan4: region counts -> chunk table + per-XCD-group chunk id lists.
__global__ void plan4_kernel(int* __restrict__ ctrl) {
    if (threadIdx.x == 0) {
        int gp[8]; for (int i = 0; i < 8; ++i) gp[i] = 0;
        int run = 0;
        for (int gi = 0; gi < NREG; ++gi) {
            int cnt = ctrl[C_SCUR + gi];
            int nc = (cnt + SC - 1) / SC;
            int x = (gi % NSLICE) & 7;           // pin by slice for dE locality
            for (int c = 0; c < nc; ++c) {
                ctrl[C_CHID + run] = (gi << 8) | c;
                ctrl[C_GRP + x * NGMAX + gp[x]] = run;
                gp[x]++; run++;
            }
        }
        for (int i = 0; i < 8; ++i) ctrl[C_GCNT + i] = gp[i];
        ctrl[C_NCH] = run;
    }
}

// fhist4: exact per-(chunk,bin) histogram table (replaces runtime reservation).
__global__ __launch_bounds__(BLK) void fhist4_kernel(
    const uint2* __restrict__ items, const int* __restrict__ ctrl,
    int* __restrict__ binHist, unsigned short* __restrict__ binCnt)
{
    __shared__ int h[NBIN];
    const int t = threadIdx.x, j = blockIdx.x;
    const int tot = ctrl[C_NCH];
    if (t < NBIN) h[t] = 0;
    __syncthreads();
    if (j < tot) {
        const int pkd = ctrl[C_CHID + j];
        const int gi = pkd >> 8, c = pkd & 255;
        const int start = gi * CAPS4 + c * SC;
        const int len = min(SC, ctrl[C_SCUR + gi] - c * SC);
        if (len == SC) {
            const vi4* p4 = (const vi4*)(items + start);
            #pragma unroll
            for (int k = 0; k < SC / (BLK * 2); ++k) {
                vi4 q = __builtin_nontemporal_load(p4 + k * BLK + t);
                atomicAdd(&h[((uint32)q.y) >> CW_BITS], 1);
                atomicAdd(&h[((uint32)q.w) >> CW_BITS], 1);
            }
        } else {
            for (int k = t; k < len; k += BLK)
                atomicAdd(&h[items[start + k].y >> CW_BITS], 1);
        }
    }
    __syncthreads();
    if (t < NBIN) {
        binHist[t * NCH4 + j] = h[t];
        binCnt[t * NCH4 + j] = (unsigned short)h[t];
    }
}

// fscan_blocks: in-place exclusive prefix across chunks per bin (+ totals).
__global__ void fscan_blocks_kernel(int* __restrict__ binHist, int* __restrict__ binTotal,
                                    int n) {
    __shared__ int s[BLK];
    const int v = blockIdx.x, t = threadIdx.x;
    int carry = 0;
    for (int c = 0; c < n; c += BLK) {
        int idx = c + t;
        int val = (idx < n) ? binHist[v * n + idx] : 0;
        s[t] = val; __syncthreads();
        for (int off = 1; off < BLK; off <<= 1) {
            int tmp = (t >= off) ? s[t - off] : 0;
            __syncthreads();
            s[t] += tmp;
            __syncthreads();
        }
        int excl = s[t] - val;
        int tot  = s[BLK - 1];
        if (idx < n) binHist[v * n + idx] = carry + excl;
        carry += tot;
        __syncthreads();
    }
    if (t == 0) binTotal[v] = carry;
}

__global__ void fbase_kernel(const int* __restrict__ binTotal, int* __restrict__ binBase) {
    __shared__ int s[BLK];
    const int t = threadIdx.x;
    int v = (t < NBIN) ? binTotal[t] : 0;
    s[t] = v; __syncthreads();
    for (int off = 1; off < BLK; off <<= 1) {
        int tmp = (t >= off) ? s[t - off] : 0;
        __syncthreads();
        s[t] += tmp;
        __syncthreads();
    }
    if (t < NBIN) binBase[t] = s[t] - v;
    if (t == 0) binBase[NBIN] = s[BLK - 1];
}

// fscatter4 v9: XCD-pinned chunks; L2-local dE gather, fused multiply, LDS
// sort, coalesced write-out. ZERO global atomics: offsets from exact tables.
__global__ __launch_bounds__(BLK) void fscatter4_kernel(
    const uint2* __restrict__ items, const float* __restrict__ dEflat,
    const int* __restrict__ ctrl, const int* __restrict__ binHist,
    const unsigned short* __restrict__ binCnt, const int* __restrict__ binBase,
    uint32* __restrict__ bm)
{
    __shared__ uint32 itl[SC];            // 32 KB
    __shared__ unsigned char bns[SC];     //  8 KB
    __shared__ int cur[NBIN], dlt[NBIN];
    __shared__ int sc[BLK];
    const int t = threadIdx.x;
    const int x = blockIdx.x & 7;         // assumed XCD (round-robin dispatch)
    const int r = blockIdx.x >> 3;
    const int gc = ctrl[C_GCNT + x];

    for (int w = r; w < gc; w += FS_PERX) {
        const int j     = ctrl[C_GRP + x * NGMAX + w];
        const int pkd   = ctrl[C_CHID + j];
        const int gi    = pkd >> 8;
        const int c     = pkd & 255;
        const int start = gi * CAPS4 + c * SC;
        const int len   = min(SC, ctrl[C_SCUR + gi] - c * SC);
        const int sl    = gi % NSLICE;
        const float* __restrict__ dE = dEflat + ((size_t)sl << SLICE_SHIFT);

        // load this chunk's bin counts + local scan; delta from exact tables
        {
            int v = (t < NBIN) ? (int)binCnt[t * NCH4 + j] : 0;
            sc[t] = v; __syncthreads();
            for (int off = 1; off < BLK; off <<= 1) {
                int tmp = (t >= off) ? sc[t - off] : 0;
                __syncthreads();
                sc[t] += tmp;
                __syncthreads();
            }
            if (t < NBIN) {
                int st = sc[t] - v;
                cur[t] = st;
                dlt[t] = binBase[t] + binHist[t * NCH4 + j] - st;
            }
        }
        __syncthreads();
        // gather (L2-local) + fused multiply + LDS sort placement
        #define PLACE4(LO, CO, DI)                                             \
        {                                                                      \
            uint32 col = (uint32)(CO);                                         \
            int bin = (int)(col >> CW_BITS);                                   \
            float val = __uint_as_float((((uint32)(LO)) >> 17) << 17);         \
            uint32 u = __float_as_uint(-val * (DI));                           \
            uint32 pk = ((col & (CW - 1)) << 20) | ((u + 0x800u) >> 12);       \
            int pos = atomicAdd(&cur[bin], 1);                                 \
            itl[pos] = pk;                                                     \
            bns[pos] = (unsigned char)bin;                                     \
        }
        if (len == SC) {
            const vi4* p4 = (const vi4*)(items + start);
            #pragma unroll 4
            for (int k = 0; k < SC / (BLK * 2); ++k) {
                vi4 q = __builtin_nontemporal_load(p4 + k * BLK + t);
                float dA = dE[((uint32)q.x) & 0x1FFFFu];
                float dB = dE[((uint32)q.z) & 0x1FFFFu];
                PLACE4(q.x, q.y, dA)
                PLACE4(q.z, q.w, dB)
            }
        } else {
            for (int k = t; k < len; k += BLK) {
                uint2 it = items[start + k];
                float d = dE[it.x & 0x1FFFFu];
                PLACE4(it.x, it.y, d)
            }
        }
        __syncthreads();
        // coalesced write-out in sorted order
        for (int i = t; i < len; i += BLK) {
            __builtin_nontemporal_store(itl[i], &bm[dlt[bns[i]] + i]);
        }
        __syncthreads();
    }
}

// fforce: per (bin, sub-slice) LDS accumulation over exactly-packed bm.
__global__ __launch_bounds__(BLK) void fforce_kernel(
    const uint32* __restrict__ bm, const int* __restrict__ binBase,
    float* __restrict__ partial)
{
    __shared__ float w[CW];
    const int t = threadIdx.x;
    const int bin = blockIdx.x >> 3;
    const int sub = blockIdx.x & (SUBS - 1);
    for (int i = t; i < CW; i += BLK) w[i] = 0.0f;
    __syncthreads();
    const int start = binBase[bin];
    const int cnt   = binBase[bin + 1] - start;
    const int sBeg  = start + (cnt * sub) / SUBS;
    const int sEnd  = start + (cnt * (sub + 1)) / SUBS;
    int i = sBeg + t;
    for (; i + 3 * BLK < sEnd; i += 4 * BLK) {
        uint32 p0 = __builtin_nontemporal_load(bm + i);
        uint32 p1 = __builtin_nontemporal_load(bm + i + BLK);
        uint32 p2 = __builtin_nontemporal_load(bm + i + 2 * BLK);
        uint32 p3 = __builtin_nontemporal_load(bm + i + 3 * BLK);
        atomicAdd(&w[p0 >> 20], __uint_as_float((p0 & 0xFFFFFu) << 12));
        atomicAdd(&w[p1 >> 20], __uint_as_float((p1 & 0xFFFFFu) << 12));
        atomicAdd(&w[p2 >> 20], __uint_as_float((p2 & 0xFFFFFu) << 12));
        atomicAdd(&w[p3 >> 20], __uint_as_float((p3 & 0xFFFFFu) << 12));
    }
    for (; i < sEnd; i += BLK) {
        uint32 p = bm[i];
        atomicAdd(&w[p >> 20], __uint_as_float((p & 0xFFFFFu) << 12));
    }
    __syncthreads();
    float* dst = partial + (size_t)blockIdx.x * CW;
    for (int k = t; k < CW; k += BLK) __builtin_nontemporal_store(w[k], dst + k);
}

__global__ void freduce_kernel(const float* __restrict__ partial, float* __restrict__ force) {
    int i = blockIdx.x * BLK + threadIdx.x;
    if (i < 3 * QTOT) {
        int bin = i >> CW_BITS, local = i & (CW - 1);
        const float* p = partial + (size_t)bin * (CW * SUBS) + local;
        float sum = 0.0f;
        #pragma unroll
        for (int k = 0; k < SUBS; ++k) sum += __builtin_nontemporal_load(p + k * CW);
        force[i] = sum;
    }
}

// ================= fallback path (small workspace) ==========================
__global__ void force_kernel(const int* __restrict__ rows, const int* __restrict__ cols,
                             const float* __restrict__ vals, const float* __restrict__ dEflat,
                             float* __restrict__ force) {
    int k = blockIdx.x * blockDim.x + threadIdx.x;
    if (k < NNZ_) {
        float contrib = -vals[k] * dEflat[rows[k]];
        atomicAdd(&force[cols[k]], contrib);
    }
}

extern "C" void kernel_launch(void* const* d_in, const int* in_sizes, int n_in,
                              void* d_out, int out_size, void* d_ws, size_t ws_size,
                              hipStream_t stream) {
    (void)in_sizes; (void)n_in; (void)out_size;
    const float* fps  = (const float*)d_in[0];
    const float* W1   = (const float*)d_in[1];
    const float* b1   = (const float*)d_in[2];
    const float* W2   = (const float*)d_in[3];
    const float* b2   = (const float*)d_in[4];
    const float* W3   = (const float*)d_in[5];
    const float* b3   = (const float*)d_in[6];
    const int*   img  = (const int*)d_in[7];
    const int*   rows = (const int*)d_in[8];
    const int*   cols = (const int*)d_in[9];
    const float* vals = (const float*)d_in[10];

    char* ws = (char*)d_ws;
    float* energy = (float*)d_out;                   // [1800]
    float* force  = (float*)d_out + NIMG_;           // [540000]
    const int nOut = NIMG_ + 3 * QTOT;

    // v9 layout (fits the proven 208,336,384 B workspace):
    //   [0, 119.85 MB)        items uint2[220*68096]   (overlay rank scratch)
    //   [0, 17.30 MB)         partial (overlay items; live after fscatter4)
    //   [119.85, 177.45)      bm uint32[NNZ] (exact)
    //   [177.45, 178.53)      binHist int[132*2048]
    //   [178.53, 179.07)      binCnt  u16[132*2048]
    //   [179.07, ...)         binTotal[132], binBase[133]
    //   [179.072, 179.095)    ctrl
    //   [179.536, 208.336)    dEflat
    int*    g_hist   = (int*)(ws);
    int*    g_total  = (int*)(ws + 5068800);
    int*    g_base   = (int*)(ws + 5076000);
    int*    rank     = (int*)(ws + 5083200);
    uint2*  items    = (uint2*)(ws);
    float*  partial4 = (float*)(ws);
    uint32* bm4      = (uint32*)(ws + 119848960);
    int*    binHist  = (int*)(ws + 177448960);
    unsigned short* binCnt = (unsigned short*)(ws + 178530304);
    int*    binTotal = (int*)(ws + 179070976);
    int*    binBase  = (int*)(ws + 179071504);
    int*    ctrl     = (int*)(ws + 179072064);
    float*  dEflat4  = (float*)(ws + 179536384);
    const size_t WS_V4 = 208336384;

    // minimal fallback layout (dEflat right after rank scratch)
    float*  dEflat5 = (float*)(ws + 5803200);
    const size_t WS_MIN = 5803200 + (size_t)QTOT * P_ * 4;

    const bool v4 = (ws_size >= WS_V4);
    float* dEflat = v4 ? dEflat4 : dEflat5;

    zero_kernel<<<(nOut + BLK - 1) / BLK, BLK, 0, stream>>>((float*)d_out, nOut);

    // atom rank (stable argsort of image_idx)
    hist_kernel<<<NB, BLK, 0, stream>>>(img, g_hist);
    scan_blocks_kernel<<<NIMG_, BLK, 0, stream>>>(g_hist, g_total);
    scan_buckets_kernel<<<1, BLK, 0, stream>>>(g_total, g_base);
    rank_kernel<<<NB, BLK, 0, stream>>>(img, g_hist, g_base, rank);

    // per-atom MLP fwd+bwd (dEflat complete after this point)
    dim3 gm((QE_ + BLK - 1) / BLK, E_);
    mlp_kernel<<<gm, BLK, 0, stream>>>(fps, W1, b1, W2, b2, W3, b3, img, rank,
                                       energy, dEflat);

    if (v4) {
        zero_ctrl_kernel<<<1, 512, 0, stream>>>(ctrl);
        slice_scatter_kernel<<<NSB, BLK, 0, stream>>>(rows, cols, vals, ctrl, items);
        plan4_kernel<<<1, BLK, 0, stream>>>(ctrl);
        fhist4_kernel<<<NCH4, BLK, 0, stream>>>(items, ctrl, binHist, binCnt);
        fscan_blocks_kernel<<<NBIN, BLK, 0, stream>>>(binHist, binTotal, NCH4);
        fbase_kernel<<<1, BLK, 0, stream>>>(binTotal, binBase);
        fscatter4_kernel<<<FS_GRID, BLK, 0, stream>>>(items, dEflat, ctrl,
                                                      binHist, binCnt, binBase, bm4);
        fforce_kernel<<<NBIN * SUBS, BLK, 0, stream>>>(bm4, binBase, partial4);
        freduce_kernel<<<(3 * QTOT + BLK - 1) / BLK, BLK, 0, stream>>>(partial4, force);
    } else if (ws_size >= WS_MIN) {
        force_kernel<<<NNZ_ / BLK, BLK, 0, stream>>>(rows, cols, vals, dEflat, force);
    }
}

// Round 8
// 613.262 us; speedup vs baseline: 1.3091x; 1.3091x over previous
//
#include <hip/hip_runtime.h>
#include <math.h>

#define E_    3
#define QE_   60000
#define QTOT  180000      // E_*QE_
#define P_    40
#define H_    20
#define NIMG_ 1800
#define NNZ_  14400000
#define BLK   256
#define NB    704         // ceil(QTOT/BLK)

// column-window partition for the sparse force accumulation
#define CW_BITS 12
#define CW      4096                  // cols per window (16 KB LDS accumulator)
#define NBIN    132                   // ceil(3*QTOT / CW)
#define SUBS    8                     // sub-slices per bin in force kernel
#define SC      8192                  // nnz items per chunk
#define NSB     1758                  // ceil(NNZ_/SC)  (input chunking)

// row-slice partition: 131072 dE rows = 512 KB per slice -> fits XCD L2
#define SLICE_SHIFT 17
#define NSLICE  55                    // ceil(7.2M / 131072)

// v9: 4-way producer split of slice cursors (cuts same-address atomic chain
// 1758 -> ~440) + exact-prepass bin offsets (cuts fscatter4's chain to ZERO)
#define GSPLIT  4
#define NREG    220                   // GSPLIT * NSLICE
#define CAPS4   68096                 // per-region item capacity (65536 + 10 sigma)
#define NCH4    2048                  // chunk-table width (actual ~1980)
#define NGMAX   384                   // per-XCD-group chunk list capacity
#define FS_GRID 1792                  // 8 XCD groups x 224 blocks
#define FS_PERX 224

// ctrl int offsets
#define C_SCUR  0      // [220]   region cursors (= counts after slice_scatter)
#define C_GCNT  256    // [8]     per-XCD-group chunk counts
#define C_NCH   264    // [1]     total chunks
#define C_CHID  512    // [2048]  chunk -> packed (region<<8)|c
#define C_GRP   2560   // [8*384] per-XCD-group chunk id lists
#define C_INTS  5632

typedef int   vi4 __attribute__((ext_vector_type(4)));
typedef float vf4 __attribute__((ext_vector_type(4)));
typedef unsigned uint32;

// ---------------- zero init -------------------------------------------------
__global__ void zero_kernel(float* __restrict__ out, int n) {
    int i = blockIdx.x * blockDim.x + threadIdx.x;
    if (i < n) out[i] = 0.0f;
}
__global__ void zero_ctrl_kernel(int* __restrict__ ctrl) {
    ctrl[threadIdx.x] = 0;   // launched with 512 threads: C_SCUR+C_GCNT+C_NCH
}

// ---------------- stable counting sort for atom ranks ----------------------
__global__ void hist_kernel(const int* __restrict__ img, int* __restrict__ g_hist) {
    __shared__ int h[NIMG_];
    const int t = threadIdx.x, b = blockIdx.x;
    for (int v = t; v < NIMG_; v += BLK) h[v] = 0;
    __syncthreads();
    int a = b * BLK + t;
    if (a < QTOT) atomicAdd(&h[img[a]], 1);
    __syncthreads();
    for (int v = t; v < NIMG_; v += BLK) g_hist[v * NB + b] = h[v];
}

__global__ void scan_blocks_kernel(int* __restrict__ g_hist, int* __restrict__ g_total) {
    __shared__ int s[BLK];
    const int v = blockIdx.x, t = threadIdx.x;
    int carry = 0;
    for (int c = 0; c < NB; c += BLK) {
        int idx = c + t;
        int val = (idx < NB) ? g_hist[v * NB + idx] : 0;
        s[t] = val; __syncthreads();
        for (int off = 1; off < BLK; off <<= 1) {
            int tmp = (t >= off) ? s[t - off] : 0;
            __syncthreads();
            s[t] += tmp;
            __syncthreads();
        }
        int excl = s[t] - val;
        int tot  = s[BLK - 1];
        if (idx < NB) g_hist[v * NB + idx] = carry + excl;
        carry += tot;
        __syncthreads();
    }
    if (t == 0) g_total[v] = carry;
}

__global__ void scan_buckets_kernel(const int* __restrict__ g_total, int* __restrict__ g_base) {
    __shared__ int s[BLK];
    const int t = threadIdx.x;
    int carry = 0;
    for (int c = 0; c < NIMG_; c += BLK) {
        int idx = c + t;
        int val = (idx < NIMG_) ? g_total[idx] : 0;
        s[t] = val; __syncthreads();
        for (int off = 1; off < BLK; off <<= 1) {
            int tmp = (t >= off) ? s[t - off] : 0;
            __syncthreads();
            s[t] += tmp;
            __syncthreads();
        }
        if (idx < NIMG_) g_base[idx] = carry + (s[t] - val);
        carry += s[BLK - 1];
        __syncthreads();
    }
}

__global__ void rank_kernel(const int* __restrict__ img, const int* __restrict__ g_hist,
                            const int* __restrict__ g_base, int* __restrict__ rank) {
    __shared__ int simg[BLK];
    const int t = threadIdx.x, b = blockIdx.x;
    int a = b * BLK + t;
    int v = (a < QTOT) ? img[a] : -1;
    simg[t] = v;
    __syncthreads();
    if (a < QTOT) {
        int local = 0;
        for (int j = 0; j < t; ++j) {
            if (simg[j] == v) local++;
        }
        rank[a] = g_base[v] + g_hist[v * NB + b] + local;
    }
}

// ---------------- per-atom MLP forward + backward ---------------------------
__global__ __launch_bounds__(BLK) void mlp_kernel(
    const float* __restrict__ fps, const float* __restrict__ W1, const float* __restrict__ b1,
    const float* __restrict__ W2, const float* __restrict__ b2, const float* __restrict__ W3,
    const float* __restrict__ b3, const int* __restrict__ img, const int* __restrict__ rank,
    float* __restrict__ energy, float* __restrict__ dEflat)
{
    __shared__ float sW1[P_ * H_], sW2[H_ * H_], sW3[H_], sB1[H_], sB2[H_];
    __shared__ float sB3;
    const int e = blockIdx.y;
    const int t = threadIdx.x;
    for (int i = t; i < P_ * H_; i += BLK) sW1[i] = W1[e * P_ * H_ + i];
    for (int i = t; i < H_ * H_; i += BLK) sW2[i] = W2[e * H_ * H_ + i];
    if (t < H_) { sW3[t] = W3[e * H_ + t]; sB1[t] = b1[e * H_ + t]; sB2[t] = b2[e * H_ + t]; }
    if (t == 0) sB3 = b3[e];
    __syncthreads();

    int q = blockIdx.x * BLK + t;
    if (q >= QE_) return;
    int a = e * QE_ + q;

    const vf4* xp = (const vf4*)(fps + (size_t)a * P_);
    float x[P_];
    #pragma unroll
    for (int p = 0; p < P_; p += 4) {
        vf4 v4 = __builtin_nontemporal_load(xp + (p >> 2));
        x[p] = v4.x; x[p+1] = v4.y; x[p+2] = v4.z; x[p+3] = v4.w;
    }

    float h1v[H_], h2v[H_];
    #pragma unroll
    for (int i = 0; i < H_; ++i) {
        float z = sB1[i];
        #pragma unroll
        for (int p = 0; p < P_; ++p) z += x[p] * sW1[p * H_ + i];
        h1v[i] = tanhf(z);
    }
    #pragma unroll
    for (int i = 0; i < H_; ++i) {
        float z = sB2[i];
        #pragma unroll
        for (int j = 0; j < H_; ++j) z += h1v[j] * sW2[j * H_ + i];
        h2v[i] = tanhf(z);
    }
    float ea = sB3;
    #pragma unroll
    for (int i = 0; i < H_; ++i) ea += h2v[i] * sW3[i];
    atomicAdd(&energy[img[a]], ea);

    float dz2[H_];
    #pragma unroll
    for (int i = 0; i < H_; ++i) dz2[i] = sW3[i] * (1.0f - h2v[i] * h2v[i]);
    float dz1[H_];
    #pragma unroll
    for (int i = 0; i < H_; ++i) {
        float d = 0.0f;
        #pragma unroll
        for (int j = 0; j < H_; ++j) d += sW2[i * H_ + j] * dz2[j];
        dz1[i] = d * (1.0f - h1v[i] * h1v[i]);
    }
    float* op = dEflat + (size_t)rank[a] * P_;
    #pragma unroll
    for (int p = 0; p < P_; p += 4) {
        float4 v4;
        float d0 = 0.f, d1 = 0.f, d2 = 0.f, d3 = 0.f;
        #pragma unroll
        for (int i = 0; i < H_; ++i) {
            d0 += sW1[(p    ) * H_ + i] * dz1[i];
            d1 += sW1[(p + 1) * H_ + i] * dz1[i];
            d2 += sW1[(p + 2) * H_ + i] * dz1[i];
            d3 += sW1[(p + 3) * H_ + i] * dz1[i];
        }
        v4.x = d0; v4.y = d1; v4.z = d2; v4.w = d3;
        *(float4*)(op + p) = v4;   // re-read by fscatter gather (L2-local)
    }
}

// ============ v9 stage A: slice_scatter with 4-way split cursors ============
// item = { (val15<<17)|rowLocal17 , col }; dest region = (blockIdx&3, slice)
__global__ __launch_bounds__(BLK) void slice_scatter_kernel(
    const int* __restrict__ rows, const int* __restrict__ cols, const float* __restrict__ vals,
    int* __restrict__ ctrl, uint2* __restrict__ items)
{
    __shared__ uint32 srow[SC];          // 32 KB staged rows
    __shared__ int h[NSLICE], lcur[NSLICE], gbase[NSLICE];
    const int t = threadIdx.x, b = blockIdx.x;
    const int g = b & (GSPLIT - 1);
    const int base = b * SC;
    const int len = min(SC, NNZ_ - base);
    const bool full = (len == SC);

    if (t < NSLICE) h[t] = 0;
    __syncthreads();
    if (full) {
        const vi4* r4 = (const vi4*)(rows + base);
        #pragma unroll
        for (int j = 0; j < SC / (BLK * 4); ++j) {
            int idx = j * BLK + t;
            vi4 rr = __builtin_nontemporal_load(r4 + idx);
            srow[idx * 4 + 0] = (uint32)rr.x; atomicAdd(&h[rr.x >> SLICE_SHIFT], 1);
            srow[idx * 4 + 1] = (uint32)rr.y; atomicAdd(&h[rr.y >> SLICE_SHIFT], 1);
            srow[idx * 4 + 2] = (uint32)rr.z; atomicAdd(&h[rr.z >> SLICE_SHIFT], 1);
            srow[idx * 4 + 3] = (uint32)rr.w; atomicAdd(&h[rr.w >> SLICE_SHIFT], 1);
        }
    } else {
        for (int j = t; j < len; j += BLK) {
            int r = rows[base + j];
            srow[j] = (uint32)r;
            atomicAdd(&h[r >> SLICE_SHIFT], 1);
        }
    }
    __syncthreads();
    if (t < NSLICE) {
        lcur[t] = 0;
        gbase[t] = (h[t] > 0) ? atomicAdd(&ctrl[C_SCUR + g * NSLICE + t], h[t]) : 0;
    }
    __syncthreads();
    if (full) {
        const vi4* c4 = (const vi4*)(cols + base);
        const vi4* v4 = (const vi4*)(vals + base);
        #pragma unroll 2
        for (int j = 0; j < SC / (BLK * 4); ++j) {
            int idx = j * BLK + t;
            vi4 cc = __builtin_nontemporal_load(c4 + idx);
            vi4 vv = __builtin_nontemporal_load(v4 + idx);
            #define EMIT(K, CI, VB)                                                \
            {                                                                      \
                uint32 r = srow[idx * 4 + K];                                      \
                int sl = (int)(r >> SLICE_SHIFT);                                  \
                int pos = gbase[sl] + atomicAdd(&lcur[sl], 1);                     \
                uint32 v15 = (((uint32)(VB)) + 0x10000u) >> 17;                    \
                items[(size_t)(g * NSLICE + sl) * CAPS4 + pos] =                   \
                    make_uint2((v15 << 17) | (r & 0x1FFFFu), (uint32)(CI));        \
            }
            EMIT(0, cc.x, vv.x)
            EMIT(1, cc.y, vv.y)
            EMIT(2, cc.z, vv.z)
            EMIT(3, cc.w, vv.w)
        }
    } else {
        for (int j = t; j < len; j += BLK) {
            uint32 r = srow[j];
            int sl = (int)(r >> SLICE_SHIFT);
            int pos = gbase[sl] + atomicAdd(&lcur[sl], 1);
            uint32 vb = ((const uint32*)vals)[base + j];
            uint32 v15 = (vb + 0x10000u) >> 17;
            items[(size_t)(g * NSLICE + sl) * CAPS4 + pos] =
                make_uint2((v15 << 17) | (r & 0x1FFFFu), (uint32)cols[base + j]);
        }
    }
}

// plan4 v10: PARALLEL region->chunk planning (v9's serial t==0 loop was 204us).
// One thread per region; per-thread prefix over <=220 LDS ints; parallel writes.
__global__ void plan4_kernel(int* __restrict__ ctrl) {
    __shared__ int nc[NREG];
    const int t = threadIdx.x;
    if (t < NREG) {
        int cnt = ctrl[C_SCUR + t];
        nc[t] = (cnt + SC - 1) / SC;
    }
    __syncthreads();
    if (t < NREG) {
        const int myx = (t % NSLICE) & 7;
        int cb = 0, gp = 0;
        for (int g2 = 0; g2 < t; ++g2) {
            int v = nc[g2];
            cb += v;
            if (((g2 % NSLICE) & 7) == myx) gp += v;
        }
        const int myn = nc[t];
        for (int c = 0; c < myn; ++c) {
            ctrl[C_CHID + cb + c] = (t << 8) | c;
            ctrl[C_GRP + myx * NGMAX + gp + c] = cb + c;
        }
    }
    if (t < 8) {
        int s = 0;
        for (int g2 = 0; g2 < NREG; ++g2)
            if (((g2 % NSLICE) & 7) == t) s += nc[g2];
        ctrl[C_GCNT + t] = s;
    }
    if (t == 0) {
        int tot = 0;
        for (int g2 = 0; g2 < NREG; ++g2) tot += nc[g2];
        ctrl[C_NCH] = tot;
    }
}

// fhist4: exact per-(chunk,bin) histogram table (replaces runtime reservation).
__global__ __launch_bounds__(BLK) void fhist4_kernel(
    const uint2* __restrict__ items, const int* __restrict__ ctrl,
    int* __restrict__ binHist, unsigned short* __restrict__ binCnt)
{
    __shared__ int h[NBIN];
    const int t = threadIdx.x, j = blockIdx.x;
    const int tot = ctrl[C_NCH];
    if (t < NBIN) h[t] = 0;
    __syncthreads();
    if (j < tot) {
        const int pkd = ctrl[C_CHID + j];
        const int gi = pkd >> 8, c = pkd & 255;
        const int start = gi * CAPS4 + c * SC;
        const int len = min(SC, ctrl[C_SCUR + gi] - c * SC);
        if (len == SC) {
            const vi4* p4 = (const vi4*)(items + start);
            #pragma unroll
            for (int k = 0; k < SC / (BLK * 2); ++k) {
                vi4 q = __builtin_nontemporal_load(p4 + k * BLK + t);
                atomicAdd(&h[((uint32)q.y) >> CW_BITS], 1);
                atomicAdd(&h[((uint32)q.w) >> CW_BITS], 1);
            }
        } else {
            for (int k = t; k < len; k += BLK)
                atomicAdd(&h[items[start + k].y >> CW_BITS], 1);
        }
    }
    __syncthreads();
    if (t < NBIN) {
        binHist[t * NCH4 + j] = h[t];
        binCnt[t * NCH4 + j] = (unsigned short)h[t];
    }
}

// fscan_blocks: in-place exclusive prefix across chunks per bin (+ totals).
__global__ void fscan_blocks_kernel(int* __restrict__ binHist, int* __restrict__ binTotal,
                                    int n) {
    __shared__ int s[BLK];
    const int v = blockIdx.x, t = threadIdx.x;
    int carry = 0;
    for (int c = 0; c < n; c += BLK) {
        int idx = c + t;
        int val = (idx < n) ? binHist[v * n + idx] : 0;
        s[t] = val; __syncthreads();
        for (int off = 1; off < BLK; off <<= 1) {
            int tmp = (t >= off) ? s[t - off] : 0;
            __syncthreads();
            s[t] += tmp;
            __syncthreads();
        }
        int excl = s[t] - val;
        int tot  = s[BLK - 1];
        if (idx < n) binHist[v * n + idx] = carry + excl;
        carry += tot;
        __syncthreads();
    }
    if (t == 0) binTotal[v] = carry;
}

__global__ void fbase_kernel(const int* __restrict__ binTotal, int* __restrict__ binBase) {
    __shared__ int s[BLK];
    const int t = threadIdx.x;
    int v = (t < NBIN) ? binTotal[t] : 0;
    s[t] = v; __syncthreads();
    for (int off = 1; off < BLK; off <<= 1) {
        int tmp = (t >= off) ? s[t - off] : 0;
        __syncthreads();
        s[t] += tmp;
        __syncthreads();
    }
    if (t < NBIN) binBase[t] = s[t] - v;
    if (t == 0) binBase[NBIN] = s[BLK - 1];
}

// fscatter4 v9: XCD-pinned chunks; L2-local dE gather, fused multiply, LDS
// sort, coalesced write-out. ZERO global atomics: offsets from exact tables.
__global__ __launch_bounds__(BLK) void fscatter4_kernel(
    const uint2* __restrict__ items, const float* __restrict__ dEflat,
    const int* __restrict__ ctrl, const int* __restrict__ binHist,
    const unsigned short* __restrict__ binCnt, const int* __restrict__ binBase,
    uint32* __restrict__ bm)
{
    __shared__ uint32 itl[SC];            // 32 KB
    __shared__ unsigned char bns[SC];     //  8 KB
    __shared__ int cur[NBIN], dlt[NBIN];
    __shared__ int sc[BLK];
    const int t = threadIdx.x;
    const int x = blockIdx.x & 7;         // assumed XCD (round-robin dispatch)
    const int r = blockIdx.x >> 3;
    const int gc = ctrl[C_GCNT + x];

    for (int w = r; w < gc; w += FS_PERX) {
        const int j     = ctrl[C_GRP + x * NGMAX + w];
        const int pkd   = ctrl[C_CHID + j];
        const int gi    = pkd >> 8;
        const int c     = pkd & 255;
        const int start = gi * CAPS4 + c * SC;
        const int len   = min(SC, ctrl[C_SCUR + gi] - c * SC);
        const int sl    = gi % NSLICE;
        const float* __restrict__ dE = dEflat + ((size_t)sl << SLICE_SHIFT);

        // load this chunk's bin counts + local scan; delta from exact tables
        {
            int v = (t < NBIN) ? (int)binCnt[t * NCH4 + j] : 0;
            sc[t] = v; __syncthreads();
            for (int off = 1; off < BLK; off <<= 1) {
                int tmp = (t >= off) ? sc[t - off] : 0;
                __syncthreads();
                sc[t] += tmp;
                __syncthreads();
            }
            if (t < NBIN) {
                int st = sc[t] - v;
                cur[t] = st;
                dlt[t] = binBase[t] + binHist[t * NCH4 + j] - st;
            }
        }
        __syncthreads();
        // gather (L2-local) + fused multiply + LDS sort placement
        #define PLACE4(LO, CO, DI)                                             \
        {                                                                      \
            uint32 col = (uint32)(CO);                                         \
            int bin = (int)(col >> CW_BITS);                                   \
            float val = __uint_as_float((((uint32)(LO)) >> 17) << 17);         \
            uint32 u = __float_as_uint(-val * (DI));                           \
            uint32 pk = ((col & (CW - 1)) << 20) | ((u + 0x800u) >> 12);       \
            int pos = atomicAdd(&cur[bin], 1);                                 \
            itl[pos] = pk;                                                     \
            bns[pos] = (unsigned char)bin;                                     \
        }
        if (len == SC) {
            const vi4* p4 = (const vi4*)(items + start);
            #pragma unroll 4
            for (int k = 0; k < SC / (BLK * 2); ++k) {
                vi4 q = __builtin_nontemporal_load(p4 + k * BLK + t);
                float dA = dE[((uint32)q.x) & 0x1FFFFu];
                float dB = dE[((uint32)q.z) & 0x1FFFFu];
                PLACE4(q.x, q.y, dA)
                PLACE4(q.z, q.w, dB)
            }
        } else {
            for (int k = t; k < len; k += BLK) {
                uint2 it = items[start + k];
                float d = dE[it.x & 0x1FFFFu];
                PLACE4(it.x, it.y, d)
            }
        }
        __syncthreads();
        // coalesced write-out in sorted order
        for (int i = t; i < len; i += BLK) {
            __builtin_nontemporal_store(itl[i], &bm[dlt[bns[i]] + i]);
        }
        __syncthreads();
    }
}

// fforce: per (bin, sub-slice) LDS accumulation over exactly-packed bm.
__global__ __launch_bounds__(BLK) void fforce_kernel(
    const uint32* __restrict__ bm, const int* __restrict__ binBase,
    float* __restrict__ partial)
{
    __shared__ float w[CW];
    const int t = threadIdx.x;
    const int bin = blockIdx.x >> 3;
    const int sub = blockIdx.x & (SUBS - 1);
    for (int i = t; i < CW; i += BLK) w[i] = 0.0f;
    __syncthreads();
    const int start = binBase[bin];
    const int cnt   = binBase[bin + 1] - start;
    const int sBeg  = start + (cnt * sub) / SUBS;
    const int sEnd  = start + (cnt * (sub + 1)) / SUBS;
    int i = sBeg + t;
    for (; i + 3 * BLK < sEnd; i += 4 * BLK) {
        uint32 p0 = __builtin_nontemporal_load(bm + i);
        uint32 p1 = __builtin_nontemporal_load(bm + i + BLK);
        uint32 p2 = __builtin_nontemporal_load(bm + i + 2 * BLK);
        uint32 p3 = __builtin_nontemporal_load(bm + i + 3 * BLK);
        atomicAdd(&w[p0 >> 20], __uint_as_float((p0 & 0xFFFFFu) << 12));
        atomicAdd(&w[p1 >> 20], __uint_as_float((p1 & 0xFFFFFu) << 12));
        atomicAdd(&w[p2 >> 20], __uint_as_float((p2 & 0xFFFFFu) << 12));
        atomicAdd(&w[p3 >> 20], __uint_as_float((p3 & 0xFFFFFu) << 12));
    }
    for (; i < sEnd; i += BLK) {
        uint32 p = bm[i];
        atomicAdd(&w[p >> 20], __uint_as_float((p & 0xFFFFFu) << 12));
    }
    __syncthreads();
    float* dst = partial + (size_t)blockIdx.x * CW;
    for (int k = t; k < CW; k += BLK) __builtin_nontemporal_store(w[k], dst + k);
}

__global__ void freduce_kernel(const float* __restrict__ partial, float* __restrict__ force) {
    int i = blockIdx.x * BLK + threadIdx.x;
    if (i < 3 * QTOT) {
        int bin = i >> CW_BITS, local = i & (CW - 1);
        const float* p = partial + (size_t)bin * (CW * SUBS) + local;
        float sum = 0.0f;
        #pragma unroll
        for (int k = 0; k < SUBS; ++k) sum += __builtin_nontemporal_load(p + k * CW);
        force[i] = sum;
    }
}

// ================= fallback path (small workspace) ==========================
__global__ void force_kernel(const int* __restrict__ rows, const int* __restrict__ cols,
                             const float* __restrict__ vals, const float* __restrict__ dEflat,
                             float* __restrict__ force) {
    int k = blockIdx.x * blockDim.x + threadIdx.x;
    if (k < NNZ_) {
        float contrib = -vals[k] * dEflat[rows[k]];
        atomicAdd(&force[cols[k]], contrib);
    }
}

extern "C" void kernel_launch(void* const* d_in, const int* in_sizes, int n_in,
                              void* d_out, int out_size, void* d_ws, size_t ws_size,
                              hipStream_t stream) {
    (void)in_sizes; (void)n_in; (void)out_size;
    const float* fps  = (const float*)d_in[0];
    const float* W1   = (const float*)d_in[1];
    const float* b1   = (const float*)d_in[2];
    const float* W2   = (const float*)d_in[3];
    const float* b2   = (const float*)d_in[4];
    const float* W3   = (const float*)d_in[5];
    const float* b3   = (const float*)d_in[6];
    const int*   img  = (const int*)d_in[7];
    const int*   rows = (const int*)d_in[8];
    const int*   cols = (const int*)d_in[9];
    const float* vals = (const float*)d_in[10];

    char* ws = (char*)d_ws;
    float* energy = (float*)d_out;                   // [1800]
    float* force  = (float*)d_out + NIMG_;           // [540000]
    const int nOut = NIMG_ + 3 * QTOT;

    // v9 layout (fits the proven 208,336,384 B workspace):
    //   [0, 119.85 MB)        items uint2[220*68096]   (overlay rank scratch)
    //   [0, 17.30 MB)         partial (overlay items; live after fscatter4)
    //   [119.85, 177.45)      bm uint32[NNZ] (exact)
    //   [177.45, 178.53)      binHist int[132*2048]
    //   [178.53, 179.07)      binCnt  u16[132*2048]
    //   [179.07, ...)         binTotal[132], binBase[133]
    //   [179.072, 179.095)    ctrl
    //   [179.536, 208.336)    dEflat
    int*    g_hist   = (int*)(ws);
    int*    g_total  = (int*)(ws + 5068800);
    int*    g_base   = (int*)(ws + 5076000);
    int*    rank     = (int*)(ws + 5083200);
    uint2*  items    = (uint2*)(ws);
    float*  partial4 = (float*)(ws);
    uint32* bm4      = (uint32*)(ws + 119848960);
    int*    binHist  = (int*)(ws + 177448960);
    unsigned short* binCnt = (unsigned short*)(ws + 178530304);
    int*    binTotal = (int*)(ws + 179070976);
    int*    binBase  = (int*)(ws + 179071504);
    int*    ctrl     = (int*)(ws + 179072064);
    float*  dEflat4  = (float*)(ws + 179536384);
    const size_t WS_V4 = 208336384;

    // minimal fallback layout (dEflat right after rank scratch)
    float*  dEflat5 = (float*)(ws + 5803200);
    const size_t WS_MIN = 5803200 + (size_t)QTOT * P_ * 4;

    const bool v4 = (ws_size >= WS_V4);
    float* dEflat = v4 ? dEflat4 : dEflat5;

    zero_kernel<<<(nOut + BLK - 1) / BLK, BLK, 0, stream>>>((float*)d_out, nOut);

    // atom rank (stable argsort of image_idx)
    hist_kernel<<<NB, BLK, 0, stream>>>(img, g_hist);
    scan_blocks_kernel<<<NIMG_, BLK, 0, stream>>>(g_hist, g_total);
    scan_buckets_kernel<<<1, BLK, 0, stream>>>(g_total, g_base);
    rank_kernel<<<NB, BLK, 0, stream>>>(img, g_hist, g_base, rank);

    // per-atom MLP fwd+bwd (dEflat complete after this point)
    dim3 gm((QE_ + BLK - 1) / BLK, E_);
    mlp_kernel<<<gm, BLK, 0, stream>>>(fps, W1, b1, W2, b2, W3, b3, img, rank,
                                       energy, dEflat);

    if (v4) {
        zero_ctrl_kernel<<<1, 512, 0, stream>>>(ctrl);
        slice_scatter_kernel<<<NSB, BLK, 0, stream>>>(rows, cols, vals, ctrl, items);
        plan4_kernel<<<1, BLK, 0, stream>>>(ctrl);
        fhist4_kernel<<<NCH4, BLK, 0, stream>>>(items, ctrl, binHist, binCnt);
        fscan_blocks_kernel<<<NBIN, BLK, 0, stream>>>(binHist, binTotal, NCH4);
        fbase_kernel<<<1, BLK, 0, stream>>>(binTotal, binBase);
        fscatter4_kernel<<<FS_GRID, BLK, 0, stream>>>(items, dEflat, ctrl,
                                                      binHist, binCnt, binBase, bm4);
        fforce_kernel<<<NBIN * SUBS, BLK, 0, stream>>>(bm4, binBase, partial4);
        freduce_kernel<<<(3 * QTOT + BLK - 1) / BLK, BLK, 0, stream>>>(partial4, force);
    } else if (ws_size >= WS_MIN) {
        force_kernel<<<NNZ_ / BLK, BLK, 0, stream>>>(rows, cols, vals, dEflat, force);
    }
}

// Round 10
// 592.447 us; speedup vs baseline: 1.3551x; 1.0351x over previous
//
#include <hip/hip_runtime.h>
#include <math.h>

#define E_    3
#define QE_   60000
#define QTOT  180000      // E_*QE_
#define P_    40
#define H_    20
#define NIMG_ 1800
#define NNZ_  14400000
#define BLK   256
#define NB    704         // ceil(QTOT/BLK)

// column-window partition for the sparse force accumulation
#define CW_BITS 12
#define CW      4096                  // cols per window (16 KB LDS accumulator)
#define NBIN    132                   // ceil(3*QTOT / CW)
#define SUBS    8                     // sub-slices per bin in force kernel
#define SC      8192                  // nnz items per chunk
#define NSB     1758                  // ceil(NNZ_/SC)  (input chunking)
#define CAPB    114688                // per-bin bm capacity (mean 109k + 16 sigma)

// row-slice partition: 131072 dE rows = 512 KB per slice -> fits XCD L2
#define SLICE_SHIFT 17
#define NSLICE  55                    // ceil(7.2M / 131072)

// v11: GSPLIT-4 producer cursors (proven R8) + R0-style in-kernel reservation
// fscatter4 (146 < 124+40 prepass). CAPS4 sized so items+bm+ctrl+dEflat fit
// the proven 208,336,384 B workspace exactly.
#define GSPLIT  4
#define NREG    220                   // GSPLIT * NSLICE
#define CAPS4   67584                 // per-region capacity (exp 65.5k, +8 sigma)
#define NCH4    2048                  // chunk id table width (actual <= 1980)
#define NGMAX   384                   // per-XCD-group chunk list capacity
#define FS_GRID 1792                  // 8 XCD groups x 224 blocks
#define FS_PERX 224

// ctrl int offsets (first 512 zeroed by zero_ctrl)
#define C_SCUR  0      // [220]   region cursors (= counts after slice_scatter)
#define C_BCUR  224    // [132]   bin cursors (= counts after fscatter4)
#define C_GCNT  360    // [8]     per-XCD-group chunk counts
#define C_NCH   368    // [1]     total chunks
#define C_CHID  512    // [2048]  chunk -> packed (region<<8)|c
#define C_GRP   2560   // [8*384] per-XCD-group chunk id lists
#define C_INTS  5632

typedef int   vi4 __attribute__((ext_vector_type(4)));
typedef float vf4 __attribute__((ext_vector_type(4)));
typedef unsigned uint32;

// ---------------- zero init -------------------------------------------------
__global__ void zero_kernel(float* __restrict__ out, int n) {
    int i = blockIdx.x * blockDim.x + threadIdx.x;
    if (i < n) out[i] = 0.0f;
}
__global__ void zero_ctrl_kernel(int* __restrict__ ctrl) {
    ctrl[threadIdx.x] = 0;   // 512 threads: covers C_SCUR, C_BCUR, C_GCNT, C_NCH
}

// ---------------- stable counting sort for atom ranks ----------------------
__global__ void hist_kernel(const int* __restrict__ img, int* __restrict__ g_hist) {
    __shared__ int h[NIMG_];
    const int t = threadIdx.x, b = blockIdx.x;
    for (int v = t; v < NIMG_; v += BLK) h[v] = 0;
    __syncthreads();
    int a = b * BLK + t;
    if (a < QTOT) atomicAdd(&h[img[a]], 1);
    __syncthreads();
    for (int v = t; v < NIMG_; v += BLK) g_hist[v * NB + b] = h[v];
}

__global__ void scan_blocks_kernel(int* __restrict__ g_hist, int* __restrict__ g_total) {
    __shared__ int s[BLK];
    const int v = blockIdx.x, t = threadIdx.x;
    int carry = 0;
    for (int c = 0; c < NB; c += BLK) {
        int idx = c + t;
        int val = (idx < NB) ? g_hist[v * NB + idx] : 0;
        s[t] = val; __syncthreads();
        for (int off = 1; off < BLK; off <<= 1) {
            int tmp = (t >= off) ? s[t - off] : 0;
            __syncthreads();
            s[t] += tmp;
            __syncthreads();
        }
        int excl = s[t] - val;
        int tot  = s[BLK - 1];
        if (idx < NB) g_hist[v * NB + idx] = carry + excl;
        carry += tot;
        __syncthreads();
    }
    if (t == 0) g_total[v] = carry;
}

__global__ void scan_buckets_kernel(const int* __restrict__ g_total, int* __restrict__ g_base) {
    __shared__ int s[BLK];
    const int t = threadIdx.x;
    int carry = 0;
    for (int c = 0; c < NIMG_; c += BLK) {
        int idx = c + t;
        int val = (idx < NIMG_) ? g_total[idx] : 0;
        s[t] = val; __syncthreads();
        for (int off = 1; off < BLK; off <<= 1) {
            int tmp = (t >= off) ? s[t - off] : 0;
            __syncthreads();
            s[t] += tmp;
            __syncthreads();
        }
        if (idx < NIMG_) g_base[idx] = carry + (s[t] - val);
        carry += s[BLK - 1];
        __syncthreads();
    }
}

__global__ void rank_kernel(const int* __restrict__ img, const int* __restrict__ g_hist,
                            const int* __restrict__ g_base, int* __restrict__ rank) {
    __shared__ int simg[BLK];
    const int t = threadIdx.x, b = blockIdx.x;
    int a = b * BLK + t;
    int v = (a < QTOT) ? img[a] : -1;
    simg[t] = v;
    __syncthreads();
    if (a < QTOT) {
        int local = 0;
        for (int j = 0; j < t; ++j) {
            if (simg[j] == v) local++;
        }
        rank[a] = g_base[v] + g_hist[v * NB + b] + local;
    }
}

// ---------------- per-atom MLP forward + backward ---------------------------
__global__ __launch_bounds__(BLK) void mlp_kernel(
    const float* __restrict__ fps, const float* __restrict__ W1, const float* __restrict__ b1,
    const float* __restrict__ W2, const float* __restrict__ b2, const float* __restrict__ W3,
    const float* __restrict__ b3, const int* __restrict__ img, const int* __restrict__ rank,
    float* __restrict__ energy, float* __restrict__ dEflat)
{
    __shared__ float sW1[P_ * H_], sW2[H_ * H_], sW3[H_], sB1[H_], sB2[H_];
    __shared__ float sB3;
    const int e = blockIdx.y;
    const int t = threadIdx.x;
    for (int i = t; i < P_ * H_; i += BLK) sW1[i] = W1[e * P_ * H_ + i];
    for (int i = t; i < H_ * H_; i += BLK) sW2[i] = W2[e * H_ * H_ + i];
    if (t < H_) { sW3[t] = W3[e * H_ + t]; sB1[t] = b1[e * H_ + t]; sB2[t] = b2[e * H_ + t]; }
    if (t == 0) sB3 = b3[e];
    __syncthreads();

    int q = blockIdx.x * BLK + t;
    if (q >= QE_) return;
    int a = e * QE_ + q;

    const vf4* xp = (const vf4*)(fps + (size_t)a * P_);
    float x[P_];
    #pragma unroll
    for (int p = 0; p < P_; p += 4) {
        vf4 v4 = __builtin_nontemporal_load(xp + (p >> 2));
        x[p] = v4.x; x[p+1] = v4.y; x[p+2] = v4.z; x[p+3] = v4.w;
    }

    float h1v[H_], h2v[H_];
    #pragma unroll
    for (int i = 0; i < H_; ++i) {
        float z = sB1[i];
        #pragma unroll
        for (int p = 0; p < P_; ++p) z += x[p] * sW1[p * H_ + i];
        h1v[i] = tanhf(z);
    }
    #pragma unroll
    for (int i = 0; i < H_; ++i) {
        float z = sB2[i];
        #pragma unroll
        for (int j = 0; j < H_; ++j) z += h1v[j] * sW2[j * H_ + i];
        h2v[i] = tanhf(z);
    }
    float ea = sB3;
    #pragma unroll
    for (int i = 0; i < H_; ++i) ea += h2v[i] * sW3[i];
    atomicAdd(&energy[img[a]], ea);

    float dz2[H_];
    #pragma unroll
    for (int i = 0; i < H_; ++i) dz2[i] = sW3[i] * (1.0f - h2v[i] * h2v[i]);
    float dz1[H_];
    #pragma unroll
    for (int i = 0; i < H_; ++i) {
        float d = 0.0f;
        #pragma unroll
        for (int j = 0; j < H_; ++j) d += sW2[i * H_ + j] * dz2[j];
        dz1[i] = d * (1.0f - h1v[i] * h1v[i]);
    }
    float* op = dEflat + (size_t)rank[a] * P_;
    #pragma unroll
    for (int p = 0; p < P_; p += 4) {
        float4 v4;
        float d0 = 0.f, d1 = 0.f, d2 = 0.f, d3 = 0.f;
        #pragma unroll
        for (int i = 0; i < H_; ++i) {
            d0 += sW1[(p    ) * H_ + i] * dz1[i];
            d1 += sW1[(p + 1) * H_ + i] * dz1[i];
            d2 += sW1[(p + 2) * H_ + i] * dz1[i];
            d3 += sW1[(p + 3) * H_ + i] * dz1[i];
        }
        v4.x = d0; v4.y = d1; v4.z = d2; v4.w = d3;
        *(float4*)(op + p) = v4;   // re-read by fscatter gather (L2-local)
    }
}

// ============ slice_scatter with 4-way split cursors (proven R8) ============
// item = { (val15<<17)|rowLocal17 , col }; dest region = (blockIdx&3, slice)
__global__ __launch_bounds__(BLK) void slice_scatter_kernel(
    const int* __restrict__ rows, const int* __restrict__ cols, const float* __restrict__ vals,
    int* __restrict__ ctrl, uint2* __restrict__ items)
{
    __shared__ uint32 srow[SC];          // 32 KB staged rows
    __shared__ int h[NSLICE], lcur[NSLICE], gbase[NSLICE];
    const int t = threadIdx.x, b = blockIdx.x;
    const int g = b & (GSPLIT - 1);
    const int base = b * SC;
    const int len = min(SC, NNZ_ - base);
    const bool full = (len == SC);

    if (t < NSLICE) h[t] = 0;
    __syncthreads();
    if (full) {
        const vi4* r4 = (const vi4*)(rows + base);
        #pragma unroll
        for (int j = 0; j < SC / (BLK * 4); ++j) {
            int idx = j * BLK + t;
            vi4 rr = __builtin_nontemporal_load(r4 + idx);
            srow[idx * 4 + 0] = (uint32)rr.x; atomicAdd(&h[rr.x >> SLICE_SHIFT], 1);
            srow[idx * 4 + 1] = (uint32)rr.y; atomicAdd(&h[rr.y >> SLICE_SHIFT], 1);
            srow[idx * 4 + 2] = (uint32)rr.z; atomicAdd(&h[rr.z >> SLICE_SHIFT], 1);
            srow[idx * 4 + 3] = (uint32)rr.w; atomicAdd(&h[rr.w >> SLICE_SHIFT], 1);
        }
    } else {
        for (int j = t; j < len; j += BLK) {
            int r = rows[base + j];
            srow[j] = (uint32)r;
            atomicAdd(&h[r >> SLICE_SHIFT], 1);
        }
    }
    __syncthreads();
    if (t < NSLICE) {
        lcur[t] = 0;
        gbase[t] = (h[t] > 0) ? atomicAdd(&ctrl[C_SCUR + g * NSLICE + t], h[t]) : 0;
    }
    __syncthreads();
    if (full) {
        const vi4* c4 = (const vi4*)(cols + base);
        const vi4* v4 = (const vi4*)(vals + base);
        #pragma unroll 2
        for (int j = 0; j < SC / (BLK * 4); ++j) {
            int idx = j * BLK + t;
            vi4 cc = __builtin_nontemporal_load(c4 + idx);
            vi4 vv = __builtin_nontemporal_load(v4 + idx);
            #define EMIT(K, CI, VB)                                                \
            {                                                                      \
                uint32 r = srow[idx * 4 + K];                                      \
                int sl = (int)(r >> SLICE_SHIFT);                                  \
                int pos = gbase[sl] + atomicAdd(&lcur[sl], 1);                     \
                uint32 v15 = (((uint32)(VB)) + 0x10000u) >> 17;                    \
                items[(size_t)(g * NSLICE + sl) * CAPS4 + pos] =                   \
                    make_uint2((v15 << 17) | (r & 0x1FFFFu), (uint32)(CI));        \
            }
            EMIT(0, cc.x, vv.x)
            EMIT(1, cc.y, vv.y)
            EMIT(2, cc.z, vv.z)
            EMIT(3, cc.w, vv.w)
        }
    } else {
        for (int j = t; j < len; j += BLK) {
            uint32 r = srow[j];
            int sl = (int)(r >> SLICE_SHIFT);
            int pos = gbase[sl] + atomicAdd(&lcur[sl], 1);
            uint32 vb = ((const uint32*)vals)[base + j];
            uint32 v15 = (vb + 0x10000u) >> 17;
            items[(size_t)(g * NSLICE + sl) * CAPS4 + pos] =
                make_uint2((v15 << 17) | (r & 0x1FFFFu), (uint32)cols[base + j]);
        }
    }
}

// plan4 (parallel, proven R8): one thread per region; per-thread prefix over
// <=220 LDS ints; parallel chunk-entry writes.
__global__ void plan4_kernel(int* __restrict__ ctrl) {
    __shared__ int nc[NREG];
    const int t = threadIdx.x;
    if (t < NREG) {
        int cnt = ctrl[C_SCUR + t];
        nc[t] = (cnt + SC - 1) / SC;
    }
    __syncthreads();
    if (t < NREG) {
        const int myx = (t % NSLICE) & 7;
        int cb = 0, gp = 0;
        for (int g2 = 0; g2 < t; ++g2) {
            int v = nc[g2];
            cb += v;
            if (((g2 % NSLICE) & 7) == myx) gp += v;
        }
        const int myn = nc[t];
        for (int c = 0; c < myn; ++c) {
            ctrl[C_CHID + cb + c] = (t << 8) | c;
            ctrl[C_GRP + myx * NGMAX + gp + c] = cb + c;
        }
    }
    if (t < 8) {
        int s = 0;
        for (int g2 = 0; g2 < NREG; ++g2)
            if (((g2 % NSLICE) & 7) == t) s += nc[g2];
        ctrl[C_GCNT + t] = s;
    }
    if (t == 0) {
        int tot = 0;
        for (int g2 = 0; g2 < NREG; ++g2) tot += nc[g2];
        ctrl[C_NCH] = tot;
    }
}

// fscatter4 v11: R0-proven two-pass in-kernel structure (hist + reservation +
// LDS sort + coalesced write-out), region indexing, regular loads so pass 2
// hits L2/L3 on pass 1's fill.
__global__ __launch_bounds__(BLK) void fscatter4_kernel(
    const uint2* __restrict__ items, const float* __restrict__ dEflat,
    int* __restrict__ ctrl, uint32* __restrict__ bm)
{
    __shared__ uint32 itl[SC];            // 32 KB
    __shared__ unsigned char bns[SC];     //  8 KB
    __shared__ int h[NBIN], cur[NBIN], dlt[NBIN];
    __shared__ int sc[BLK];
    const int t = threadIdx.x;
    const int x = blockIdx.x & 7;         // assumed XCD (round-robin dispatch)
    const int r = blockIdx.x >> 3;
    const int gc = ctrl[C_GCNT + x];

    for (int w = r; w < gc; w += FS_PERX) {
        const int j     = ctrl[C_GRP + x * NGMAX + w];
        const int pkd   = ctrl[C_CHID + j];
        const int gi    = pkd >> 8;
        const int c     = pkd & 255;
        const int start = gi * CAPS4 + c * SC;
        const int len   = min(SC, ctrl[C_SCUR + gi] - c * SC);
        const int sl    = gi % NSLICE;
        const float* __restrict__ dE = dEflat + ((size_t)sl << SLICE_SHIFT);

        if (t < NBIN) h[t] = 0;
        __syncthreads();
        // pass 1: histogram over cols (regular loads -> fills L2 for pass 2)
        if (len == SC) {
            const vi4* p4 = (const vi4*)(items + start);
            #pragma unroll
            for (int k = 0; k < SC / (BLK * 2); ++k) {
                vi4 q = p4[k * BLK + t];
                atomicAdd(&h[((uint32)q.y) >> CW_BITS], 1);
                atomicAdd(&h[((uint32)q.w) >> CW_BITS], 1);
            }
        } else {
            for (int k = t; k < len; k += BLK)
                atomicAdd(&h[items[start + k].y >> CW_BITS], 1);
        }
        __syncthreads();
        // local scan -> cur; global capacity reservation -> dlt
        {
            int v = (t < NBIN) ? h[t] : 0;
            sc[t] = v; __syncthreads();
            for (int off = 1; off < BLK; off <<= 1) {
                int tmp = (t >= off) ? sc[t - off] : 0;
                __syncthreads();
                sc[t] += tmp;
                __syncthreads();
            }
            if (t < NBIN) {
                int ls = sc[t] - v;
                cur[t] = ls;
                int gb = (v > 0) ? atomicAdd(&ctrl[C_BCUR + t], v) : 0;
                dlt[t] = t * CAPB + gb - ls;
            }
        }
        __syncthreads();
        // pass 2: gather (L2-local) + fused multiply + LDS sort placement
        #define PLACE4(LO, CO, DI)                                             \
        {                                                                      \
            uint32 col = (uint32)(CO);                                         \
            int bin = (int)(col >> CW_BITS);                                   \
            float val = __uint_as_float((((uint32)(LO)) >> 17) << 17);         \
            uint32 u = __float_as_uint(-val * (DI));                           \
            uint32 pk = ((col & (CW - 1)) << 20) | ((u + 0x800u) >> 12);       \
            int pos = atomicAdd(&cur[bin], 1);                                 \
            itl[pos] = pk;                                                     \
            bns[pos] = (unsigned char)bin;                                     \
        }
        if (len == SC) {
            const vi4* p4 = (const vi4*)(items + start);
            #pragma unroll 2
            for (int k = 0; k < SC / (BLK * 2); ++k) {
                vi4 q = p4[k * BLK + t];
                float dA = dE[((uint32)q.x) & 0x1FFFFu];
                float dB = dE[((uint32)q.z) & 0x1FFFFu];
                PLACE4(q.x, q.y, dA)
                PLACE4(q.z, q.w, dB)
            }
        } else {
            for (int k = t; k < len; k += BLK) {
                uint2 it = items[start + k];
                float d = dE[it.x & 0x1FFFFu];
                PLACE4(it.x, it.y, d)
            }
        }
        __syncthreads();
        // coalesced write-out in sorted order (regular store -> L3 for fforce)
        for (int i = t; i < len; i += BLK) {
            bm[dlt[bns[i]] + i] = itl[i];
        }
        __syncthreads();
    }
}

// fforce: per (bin, sub-slice) LDS accumulation over capacity-based bm.
__global__ __launch_bounds__(BLK) void fforce_kernel(
    const uint32* __restrict__ bm, const int* __restrict__ ctrl,
    float* __restrict__ partial)
{
    __shared__ float w[CW];
    const int t = threadIdx.x;
    const int bin = blockIdx.x >> 3;
    const int sub = blockIdx.x & (SUBS - 1);
    for (int i = t; i < CW; i += BLK) w[i] = 0.0f;
    __syncthreads();
    const int cnt   = ctrl[C_BCUR + bin];
    const int start = bin * CAPB;
    const int sBeg  = start + (cnt * sub) / SUBS;
    const int sEnd  = start + (cnt * (sub + 1)) / SUBS;
    int i = sBeg + t;
    for (; i + 3 * BLK < sEnd; i += 4 * BLK) {
        uint32 p0 = bm[i];
        uint32 p1 = bm[i + BLK];
        uint32 p2 = bm[i + 2 * BLK];
        uint32 p3 = bm[i + 3 * BLK];
        atomicAdd(&w[p0 >> 20], __uint_as_float((p0 & 0xFFFFFu) << 12));
        atomicAdd(&w[p1 >> 20], __uint_as_float((p1 & 0xFFFFFu) << 12));
        atomicAdd(&w[p2 >> 20], __uint_as_float((p2 & 0xFFFFFu) << 12));
        atomicAdd(&w[p3 >> 20], __uint_as_float((p3 & 0xFFFFFu) << 12));
    }
    for (; i < sEnd; i += BLK) {
        uint32 p = bm[i];
        atomicAdd(&w[p >> 20], __uint_as_float((p & 0xFFFFFu) << 12));
    }
    __syncthreads();
    float* dst = partial + (size_t)blockIdx.x * CW;
    for (int k = t; k < CW; k += BLK) __builtin_nontemporal_store(w[k], dst + k);
}

__global__ void freduce_kernel(const float* __restrict__ partial, float* __restrict__ force) {
    int i = blockIdx.x * BLK + threadIdx.x;
    if (i < 3 * QTOT) {
        int bin = i >> CW_BITS, local = i & (CW - 1);
        const float* p = partial + (size_t)bin * (CW * SUBS) + local;
        float sum = 0.0f;
        #pragma unroll
        for (int k = 0; k < SUBS; ++k) sum += __builtin_nontemporal_load(p + k * CW);
        force[i] = sum;
    }
}

// ================= fallback path (small workspace) ==========================
__global__ void force_kernel(const int* __restrict__ rows, const int* __restrict__ cols,
                             const float* __restrict__ vals, const float* __restrict__ dEflat,
                             float* __restrict__ force) {
    int k = blockIdx.x * blockDim.x + threadIdx.x;
    if (k < NNZ_) {
        float contrib = -vals[k] * dEflat[rows[k]];
        atomicAdd(&force[cols[k]], contrib);
    }
}

extern "C" void kernel_launch(void* const* d_in, const int* in_sizes, int n_in,
                              void* d_out, int out_size, void* d_ws, size_t ws_size,
                              hipStream_t stream) {
    (void)in_sizes; (void)n_in; (void)out_size;
    const float* fps  = (const float*)d_in[0];
    const float* W1   = (const float*)d_in[1];
    const float* b1   = (const float*)d_in[2];
    const float* W2   = (const float*)d_in[3];
    const float* b2   = (const float*)d_in[4];
    const float* W3   = (const float*)d_in[5];
    const float* b3   = (const float*)d_in[6];
    const int*   img  = (const int*)d_in[7];
    const int*   rows = (const int*)d_in[8];
    const int*   cols = (const int*)d_in[9];
    const float* vals = (const float*)d_in[10];

    char* ws = (char*)d_ws;
    float* energy = (float*)d_out;                   // [1800]
    float* force  = (float*)d_out + NIMG_;           // [540000]
    const int nOut = NIMG_ + 3 * QTOT;

    // v11 layout (fits 208,336,384 B exactly):
    //   [0, 118.95 MB)        items uint2[220*67584]   (overlay rank scratch)
    //   [0, 17.30 MB)         partial (overlay items; live after fscatter4)
    //   [118.95, 179.50)      bm uint32[132*CAPB]
    //   [179.503, 179.526)    ctrl (C_INTS=5632 ints)
    //   [179.536, 208.336)    dEflat
    int*    g_hist   = (int*)(ws);
    int*    g_total  = (int*)(ws + 5068800);
    int*    g_base   = (int*)(ws + 5076000);
    int*    rank     = (int*)(ws + 5083200);
    uint2*  items    = (uint2*)(ws);
    float*  partial4 = (float*)(ws);
    uint32* bm4      = (uint32*)(ws + 118947840);
    int*    ctrl     = (int*)(ws + 179503104);
    float*  dEflat4  = (float*)(ws + 179536384);
    const size_t WS_V4 = 208336384;

    // minimal fallback layout (dEflat right after rank scratch)
    float*  dEflat5 = (float*)(ws + 5803200);
    const size_t WS_MIN = 5803200 + (size_t)QTOT * P_ * 4;

    const bool v4 = (ws_size >= WS_V4);
    float* dEflat = v4 ? dEflat4 : dEflat5;

    // fast path: only energy needs zeroing (freduce fully writes force)
    if (v4) {
        zero_kernel<<<(NIMG_ + BLK - 1) / BLK, BLK, 0, stream>>>(energy, NIMG_);
    } else {
        zero_kernel<<<(nOut + BLK - 1) / BLK, BLK, 0, stream>>>((float*)d_out, nOut);
    }

    // atom rank (stable argsort of image_idx)
    hist_kernel<<<NB, BLK, 0, stream>>>(img, g_hist);
    scan_blocks_kernel<<<NIMG_, BLK, 0, stream>>>(g_hist, g_total);
    scan_buckets_kernel<<<1, BLK, 0, stream>>>(g_total, g_base);
    rank_kernel<<<NB, BLK, 0, stream>>>(img, g_hist, g_base, rank);

    // per-atom MLP fwd+bwd (dEflat complete after this point)
    dim3 gm((QE_ + BLK - 1) / BLK, E_);
    mlp_kernel<<<gm, BLK, 0, stream>>>(fps, W1, b1, W2, b2, W3, b3, img, rank,
                                       energy, dEflat);

    if (v4) {
        zero_ctrl_kernel<<<1, 512, 0, stream>>>(ctrl);
        slice_scatter_kernel<<<NSB, BLK, 0, stream>>>(rows, cols, vals, ctrl, items);
        plan4_kernel<<<1, BLK, 0, stream>>>(ctrl);
        fscatter4_kernel<<<FS_GRID, BLK, 0, stream>>>(items, dEflat, ctrl, bm4);
        fforce_kernel<<<NBIN * SUBS, BLK, 0, stream>>>(bm4, ctrl, partial4);
        freduce_kernel<<<(3 * QTOT + BLK - 1) / BLK, BLK, 0, stream>>>(partial4, force);
    } else if (ws_size >= WS_MIN) {
        force_kernel<<<NNZ_ / BLK, BLK, 0, stream>>>(rows, cols, vals, dEflat, force);
    }
}